// Round 6
// baseline (321.695 us; speedup 1.0000x reference)
//
#include <hip/hip_runtime.h>
#include <hip/hip_bf16.h>

typedef short short8 __attribute__((ext_vector_type(8)));
typedef float float4v __attribute__((ext_vector_type(4)));

// ws layout: [0, 32KB) = We2 in bf16 MFMA-B-fragment order (16384 shorts)
//            float* F = (float*)ws + 8192, offsets below (in floats)
//            flag pair (uint2) at byte offset 1MB (poison-robust protocol)
#define WS_T   0        // T[21][128]
#define WS_D   2688     // be2+bl2+br2+cr0
#define WS_C   2816     // cl0
#define WS_A2  3072     // a2
#define WS_G   7296     // G[21][21] = rows of T folded through W_out
#define WS_B0  7744     // b_out + W_out^T @ O   (21)
#define WS_B1  7776     // W_out^T @ cl0         (21)
#define WS_M   7808     // packed per-node meta: float2 { key[n], bitcast S[n] }
#define N_ROLE 102
#define FLAG_BYTE_OFF (1u << 20)

__device__ __forceinline__ unsigned int pack2bf(float a, float b) {
  // two fp32 -> packed bf16 pair (round-half-up; differs from RNE only on ties)
  union { float f; unsigned int u; } xa, xb;
  xa.f = a; xb.f = b;
  return ((xa.u + 0x8000u) >> 16) | ((xb.u + 0x8000u) & 0xFFFF0000u);
}

// ---------------------------------------------------------------------------
// Single fused kernel (grid 1024 x 256 = exactly 4 blocks/CU x 256 CU, all
// co-resident: launch_bounds caps VGPR at 128 => 4 blocks/CU; LDS 34.8KB).
//
//  Blocks 0..101 run producer roles FIRST (We2 swizzle / T,G tables / meta /
//  constants -- all trivially parallel), then release-increment a flag.
//  ALL blocks then stream their E tiles to A-fragments (~10.7us of HBM, no
//  ws dependency) -- the producer work hides under this stream. A leader
//  acquire-spin + block barrier gates the ws-dependent tail.
//
//  Poison-robust flag: harness poison-fills ws UNIFORMLY each iteration, so
//  flag[1] (never written) holds the fill value; done <=> flag[0]-flag[1]
//  == N_ROLE. Correct for any fill pattern; idempotent if launched twice
//  without re-poison (producers rewrite identical values). Bounded spin
//  turns any protocol failure into a visible wrong-answer, not a hang.
// ---------------------------------------------------------------------------
__global__ __launch_bounds__(256, 4) void pg15_fused(
    const float* __restrict__ E, const int* __restrict__ E_idx,
    const float* __restrict__ mask, const float* __restrict__ chain_M,
    const float* __restrict__ z, const int* __restrict__ S,
    const float* __restrict__ Wl2, const float* __restrict__ Wr2,
    const float* __restrict__ We2, const float* __restrict__ bl1,
    const float* __restrict__ bl2, const float* __restrict__ br2,
    const float* __restrict__ be2, const float* __restrict__ a2,
    const float* __restrict__ bo1, const float* __restrict__ bo2,
    const float* __restrict__ W_s, const float* __restrict__ W_out,
    const float* __restrict__ b_out, void* __restrict__ ws,
    float* __restrict__ out)
{
  __shared__ __align__(16) short ldsW[16384];   // 32 KB: We2 B-fragments
  __shared__ float sA[128], sB[128], sP[2][128];

  short* wsW = (short*)ws;
  float* F = (float*)ws + 8192;
  unsigned int* flag = (unsigned int*)((char*)ws + FLAG_BYTE_OFF);

  const int b    = blockIdx.x, tid = threadIdx.x;
  const int wave = tid >> 6;
  const int lane = tid & 63;
  const int quad = lane >> 4;
  const int lid  = lane & 15;
  const int n    = b * 4 + wave;
  const float maskn = mask[n];

  // --- edge indices: independent of ws, issue first
  int jidx = 0;
  if (lane < 32) jidx = E_idx[n * 32 + lane];

  // ======== producer roles (blocks 0..101), before own E staging ==========
  if (b < N_ROLE) {
    if (b < 64) {
      // We2 swizzle: one 256-element slice per block (coalesced read)
      const int s = b * 256 + tid;
      const int row = s >> 7, c = s & 127;          // row = K idx, c = N idx
      const int q = row >> 5, lh = (row & 31) >> 3, j = row & 7;
      const int t = c >> 4, cl = c & 15;
      union { float f; unsigned int u; } x; x.f = We2[s];
      const unsigned int r = x.u + 0x7FFFu + ((x.u >> 16) & 1u);  // RNE
      wsW[(((q * 8 + t) * 64) + lh * 16 + cl) * 8 + j] = (short)(r >> 16);
    } else if (b < 85) {
      // T[v] (K-dim split over thread halves), then G[v]
      const int v = b - 64;                          // 0..20, race-free
      const int half = tid >> 7, c = tid & 127;
      float acc = 0.f;
#pragma unroll 8
      for (int h = half * 64; h < half * 64 + 64; h++)
        acc += W_s[v * 128 + h] * Wl2[(128 + h) * 128 + c];
      sP[half][c] = acc;
      __syncthreads();
      if (tid < 128) {
        const float t = sP[0][tid] + sP[1][tid];
        F[WS_T + v * 128 + tid] = t;
        sA[tid] = t;
      }
      __syncthreads();
      if (tid < 42) {
        const int u  = (tid < 21) ? tid : tid - 21;
        const int h2 = (tid < 21) ? 0 : 1;
        float g = 0.f;
        for (int c2 = h2 * 64; c2 < h2 * 64 + 64; c2++)
          g = fmaf(sA[c2], W_out[c2 * 21 + u], g);
        sB[tid] = g;
      }
      __syncthreads();
      if (tid < 21)
        F[WS_G + v * 21 + tid] = sB[tid] + sB[21 + tid];
    } else if (b < 101) {
      // packed per-node meta (single float2 gather target for consumers)
      const int nn = (b - 85) * 256 + tid;
      F[WS_M + 2 * nn] = (chain_M[nn] * mask[nn] + 1e-4f) * fabsf(z[nn]);
      ((int*)F)[WS_M + 2 * nn + 1] = S[nn];
    } else {
      // collapsed constants: cl0 (threads 0-127) and cr0 (threads 128-255)
      if (tid < 128) {
        const int c = tid;
        float cl0 = 0.f;
#pragma unroll 8
        for (int i = 0; i < 128; i++)
          cl0 += (bl1[i] + bo1[i]) * Wl2[i * 128 + c];
        F[WS_C + c] = cl0;
        sB[c] = cl0;
      } else {
        const int c = tid - 128;
        float cr0 = 0.f;
#pragma unroll 8
        for (int i = 0; i < 128; i++)
          cr0 += (bl1[i] + bo1[i]) * Wr2[i * 128 + c];
        F[WS_D + c]  = be2[c] + bl2[c] + br2[c] + cr0;
        F[WS_A2 + c] = a2[c];
        sA[c] = bl2[c] + bo2[c];         // O vector (only needed for B0 fold)
      }
      __syncthreads();
      if (tid < 21) {
        float b0 = b_out[tid];
        for (int c = 0; c < 128; c++)
          b0 = fmaf(sA[c], W_out[c * 21 + tid], b0);
        F[WS_B0 + tid] = b0;
      } else if (tid >= 64 && tid < 85) {
        const int u = tid - 64;
        float b1 = 0.f;
        for (int c = 0; c < 128; c++)
          b1 = fmaf(sB[c], W_out[c * 21 + u], b1);
        F[WS_B1 + u] = b1;
      }
    }
    __syncthreads();   // all role stores retired before the release
    if (tid == 0)
      __hip_atomic_fetch_add(flag, 1u, __ATOMIC_RELEASE,
                             __HIP_MEMORY_SCOPE_AGENT);
  }

  // ======== A fragments straight from global E (bulk HBM stream) ==========
  const float* rowp = E + (size_t)n * 4096 + (size_t)lid * 128 + quad * 8;
  short8 afr[2][4];
#pragma unroll
  for (int g = 0; g < 2; g++)
#pragma unroll
    for (int q = 0; q < 4; q++) {
      const float* p = rowp + g * 2048 + q * 32;
      const float4 A = *(const float4*)p;
      const float4 B = *(const float4*)(p + 4);
      union { short8 s; unsigned int u[4]; } v;
      v.u[0] = pack2bf(A.x, A.y);
      v.u[1] = pack2bf(A.z, A.w);
      v.u[2] = pack2bf(B.x, B.y);
      v.u[3] = pack2bf(B.z, B.w);
      afr[g][q] = v.s;
    }

  // ======== wait for producers (leader acquire-spin, bounded) =============
  if (tid == 0) {
    const unsigned int initv =
        __hip_atomic_load(flag + 1, __ATOMIC_RELAXED, __HIP_MEMORY_SCOPE_AGENT);
    int guard = 0;
    while ((unsigned int)(__hip_atomic_load(flag, __ATOMIC_ACQUIRE,
                              __HIP_MEMORY_SCOPE_AGENT) - initv)
               < (unsigned int)N_ROLE) {
      __builtin_amdgcn_s_sleep(2);
      if (++guard > (1 << 20)) break;   // fail visibly, never hang
    }
  }
  __syncthreads();

  // ======== ws-dependent tail =============================================
  // stage swizzled We2 into LDS (linear copy, lane-consecutive 16B)
#pragma unroll
  for (int i = 0; i < 8; i++) {
    const int c = i * 256 + tid;               // short8 chunk id, 2048 total
    *(short8*)(ldsW + c * 8) = *(const short8*)(wsW + c * 8);
  }

  // edge meta: one packed float2 gather per edge
  float wkv = 0.f; int rvv = 0;
  const float keyn = F[WS_M + 2 * n];
  if (lane < 32) {
    const float2 mj = *(const float2*)(F + WS_M + 2 * jidx);
    // stable argsort: j ordered before n  <=>  (key[j], j) <lex (key[n], n)
    const int before = (mj.x < keyn) || (mj.x == keyn && jidx < n);
    wkv = before ? maskn : 0.f;
    union { float f; int i; } cv; cv.f = mj.y; rvv = cv.i;
  }
  int rows[2][4]; float wks[2][4];
#pragma unroll
  for (int g = 0; g < 2; g++)
#pragma unroll
    for (int r = 0; r < 4; r++) {
      const int kk = g * 16 + quad * 4 + r;
      rows[g][r] = __shfl(rvv, kk) * 128;
      wks[g][r]  = __shfl(wkv, kk);
    }

  __syncthreads();   // ldsW ready

  // K-loop: B tiles from LDS; dvt/a2t INSIDE the loop (r5 hoist reverted:
  // +16 VGPR at peak pressure cost ~2us under the 128-VGPR cap)
  float part[2][4] = {{0.f, 0.f, 0.f, 0.f}, {0.f, 0.f, 0.f, 0.f}};
#pragma unroll
  for (int t = 0; t < 8; t++) {
    short8 bfr[4];
#pragma unroll
    for (int q = 0; q < 4; q++)
      bfr[q] = *(const short8*)(ldsW + (((q * 8 + t) * 64) + lane) * 8);
    float4v ac0 = {0.f, 0.f, 0.f, 0.f}, ac1 = {0.f, 0.f, 0.f, 0.f};
#pragma unroll
    for (int q = 0; q < 4; q++) {
      ac0 = __builtin_amdgcn_mfma_f32_16x16x32_bf16(afr[0][q], bfr[q], ac0, 0, 0, 0);
      ac1 = __builtin_amdgcn_mfma_f32_16x16x32_bf16(afr[1][q], bfr[q], ac1, 0, 0, 0);
    }
    const int c = t * 16 + lid;
    const float dvt  = F[WS_D + c] + maskn * F[WS_C + c];
    const float a2vt = F[WS_A2 + c];
#pragma unroll
    for (int r = 0; r < 4; r++) {
      float v0 = ac0[r] + dvt + wks[0][r] * F[WS_T + rows[0][r] + c];
      float v1 = ac1[r] + dvt + wks[1][r] * F[WS_T + rows[1][r] + c];
      v0 = fmaxf(v0, 0.f) + 0.2f * fminf(v0, 0.f);   // leaky_relu(0.2)
      v1 = fmaxf(v1, 0.f) + 0.2f * fminf(v1, 0.f);
      part[0][r] = fmaf(v0, a2vt, part[0][r]);
      part[1][r] = fmaf(v1, a2vt, part[1][r]);
    }
  }
  // reduce scores over the 16 c-lanes of each quad
  float sreg[2][4];
#pragma unroll
  for (int g = 0; g < 2; g++)
#pragma unroll
    for (int r = 0; r < 4; r++) {
      float v = part[g][r];
      v += __shfl_xor(v, 1);
      v += __shfl_xor(v, 2);
      v += __shfl_xor(v, 4);
      v += __shfl_xor(v, 8);
      sreg[g][r] = v;   // score for edge kk = g*16 + quad*4 + r (uniform in quad)
    }

  // softmax over 32 neighbor scores
  float mx = -1e30f;
#pragma unroll
  for (int g = 0; g < 2; g++)
#pragma unroll
    for (int r = 0; r < 4; r++) mx = fmaxf(mx, sreg[g][r]);
  mx = fmaxf(mx, __shfl_xor(mx, 16));
  mx = fmaxf(mx, __shfl_xor(mx, 32));
  float eg[2][4], esum = 0.f;
#pragma unroll
  for (int g = 0; g < 2; g++)
#pragma unroll
    for (int r = 0; r < 4; r++) {
      eg[g][r] = expf(sreg[g][r] - mx);
      esum += eg[g][r];
    }
  esum += __shfl_xor(esum, 16);
  esum += __shfl_xor(esum, 32);
  const float inv = 1.f / esum;
  float cg[2][4];
#pragma unroll
  for (int g = 0; g < 2; g++)
#pragma unroll
    for (int r = 0; r < 4; r++) cg[g][r] = eg[g][r] * inv * wks[g][r];

  // logits via 21x21 table: lg[u] = base0 + maskn*base1 + sum_k cf_k*G[S_k][u]
  float lg = (lane < 21) ? (F[WS_B0 + lane] + maskn * F[WS_B1 + lane]) : -1e30f;
#pragma unroll
  for (int kk = 0; kk < 32; kk++) {
    const int g = kk >> 4, sq = (kk >> 2) & 3, r = kk & 3;
    const float cf = __shfl(cg[g][r], sq * 16);     // broadcast from source quad
    const int row = __shfl(rvv, kk) * 21;           // edge's S from lane kk
    if (lane < 21) lg = fmaf(cf, F[WS_G + row + lane], lg);
  }

  // log_softmax over V=21
  float lmx = lg;
  lmx = fmaxf(lmx, __shfl_xor(lmx, 1));
  lmx = fmaxf(lmx, __shfl_xor(lmx, 2));
  lmx = fmaxf(lmx, __shfl_xor(lmx, 4));
  lmx = fmaxf(lmx, __shfl_xor(lmx, 8));
  lmx = fmaxf(lmx, __shfl_xor(lmx, 16));
  float ex = (lane < 21) ? expf(lg - lmx) : 0.f;
  float es = ex;
  es += __shfl_xor(es, 1);
  es += __shfl_xor(es, 2);
  es += __shfl_xor(es, 4);
  es += __shfl_xor(es, 8);
  es += __shfl_xor(es, 16);
  if (lane < 21)
    out[n * 21 + lane] = lg - lmx - logf(es);
}

extern "C" void kernel_launch(void* const* d_in, const int* in_sizes, int n_in,
                              void* d_out, int out_size, void* d_ws, size_t ws_size,
                              hipStream_t stream)
{
  const float* E       = (const float*)d_in[0];
  const int*   E_idx   = (const int*)d_in[1];
  const int*   S       = (const int*)d_in[2];
  const float* mask    = (const float*)d_in[3];
  const float* chain_M = (const float*)d_in[4];
  const float* z       = (const float*)d_in[5];
  const float* bl1     = (const float*)d_in[7];
  const float* bo1     = (const float*)d_in[13];
  const float* Wl2     = (const float*)d_in[14];
  const float* bl2     = (const float*)d_in[15];
  const float* Wr2     = (const float*)d_in[16];
  const float* br2     = (const float*)d_in[17];
  const float* We2     = (const float*)d_in[18];
  const float* be2     = (const float*)d_in[19];
  const float* a2      = (const float*)d_in[20];
  const float* bo2     = (const float*)d_in[21];
  const float* W_s     = (const float*)d_in[22];
  const float* W_out   = (const float*)d_in[23];
  const float* b_out   = (const float*)d_in[24];

  pg15_fused<<<1024, 256, 0, stream>>>(E, E_idx, mask, chain_M, z, S,
                                       Wl2, Wr2, We2, bl1, bl2, br2, be2,
                                       a2, bo1, bo2, W_s, W_out, b_out,
                                       d_ws, (float*)d_out);
}

// Round 8
// 155.594 us; speedup vs baseline: 2.0675x; 2.0675x over previous
//
#include <hip/hip_runtime.h>
#include <hip/hip_bf16.h>

typedef short short8 __attribute__((ext_vector_type(8)));
typedef float float4v __attribute__((ext_vector_type(4)));

// ws layout: [0, 32KB) = We2 in bf16 MFMA-B-fragment order (16384 shorts)
//            float* F = (float*)ws + 8192, offsets below (in floats)
#define WS_T   0        // T[21][128]
#define WS_D   2688     // be2+bl2+br2+cr0
#define WS_C   2816     // cl0
#define WS_A2  3072     // a2
#define WS_G   7296     // G[21][21] = rows of T folded through W_out
#define WS_B0  7744     // b_out + W_out^T @ O   (21)
#define WS_B1  7776     // W_out^T @ cl0         (21)
#define WS_M   7808     // packed per-node meta: float2 { key[n], bitcast S[n] }

__device__ __forceinline__ unsigned int pack2bf(float a, float b) {
  // two fp32 -> packed bf16 pair (round-half-up; differs from RNE only on ties)
  union { float f; unsigned int u; } xa, xb;
  xa.f = a; xb.f = b;
  return ((xa.u + 0x8000u) >> 16) | ((xb.u + 0x8000u) & 0xFFFF0000u);
}

// ---------------------------------------------------------------------------
// Prologue (grid 102 x 256), fully parallel, race-free role ranges:
//  blocks 0..63  : We2 swizzle into bf16 B-fragment order (256 elems each)
//  blocks 64..84 : v = b-64 (0..20): T[v] = W_s[v] @ Wl2[128:,:] (K split
//                  across thread halves), then G[v] = W_out^T T[v]
//  blocks 85..100: packed meta M[n] = (decoding key[n], S[n]), 256 nodes each
//  block 101     : collapsed constants; cl0/cr0 on disjoint thread halves,
//                  B0/B1 folds on two parallel warps
// ---------------------------------------------------------------------------
__global__ __launch_bounds__(256) void pg16_pre(
    const float* __restrict__ Wl2, const float* __restrict__ Wr2,
    const float* __restrict__ We2, const float* __restrict__ bl1,
    const float* __restrict__ bl2, const float* __restrict__ br2,
    const float* __restrict__ be2, const float* __restrict__ a2,
    const float* __restrict__ bo1, const float* __restrict__ bo2,
    const float* __restrict__ W_s, const float* __restrict__ mask,
    const float* __restrict__ chain_M, const float* __restrict__ z,
    const int* __restrict__ S, const float* __restrict__ W_out,
    const float* __restrict__ b_out, void* __restrict__ ws)
{
  __shared__ float sA[128], sB[128], sP[2][128];
  short* wsW = (short*)ws;
  float* F = (float*)ws + 8192;
  const int b = blockIdx.x, tid = threadIdx.x;

  if (b < 64) {
    // --- We2 swizzle: one 256-element slice per block (coalesced read)
    const int s = b * 256 + tid;
    const int row = s >> 7, c = s & 127;            // row = K idx, c = N idx
    const int q = row >> 5, lh = (row & 31) >> 3, j = row & 7;
    const int t = c >> 4, cl = c & 15;
    union { float f; unsigned int u; } x; x.f = We2[s];
    const unsigned int r = x.u + 0x7FFFu + ((x.u >> 16) & 1u);  // RNE
    wsW[(((q * 8 + t) * 64) + lh * 16 + cl) * 8 + j] = (short)(r >> 16);
  } else if (b < 85) {
    // --- T[v] (K-dim split over thread halves), then G[v]
    const int v = b - 64;                            // 0..20 only (race-free)
    const int half = tid >> 7, c = tid & 127;
    float acc = 0.f;
#pragma unroll 8
    for (int h = half * 64; h < half * 64 + 64; h++)
      acc += W_s[v * 128 + h] * Wl2[(128 + h) * 128 + c];
    sP[half][c] = acc;
    __syncthreads();
    if (tid < 128) {
      const float t = sP[0][tid] + sP[1][tid];
      F[WS_T + v * 128 + tid] = t;
      sA[tid] = t;
    }
    __syncthreads();
    if (tid < 42) {
      const int u  = (tid < 21) ? tid : tid - 21;
      const int h2 = (tid < 21) ? 0 : 1;
      float g = 0.f;
      for (int c2 = h2 * 64; c2 < h2 * 64 + 64; c2++)
        g = fmaf(sA[c2], W_out[c2 * 21 + u], g);
      sB[tid] = g;
    }
    __syncthreads();
    if (tid < 21)
      F[WS_G + v * 21 + tid] = sB[tid] + sB[21 + tid];
  } else if (b < 101) {
    // --- packed per-node meta (single float2 gather target for main)
    const int n = (b - 85) * 256 + tid;
    F[WS_M + 2 * n] = (chain_M[n] * mask[n] + 1e-4f) * fabsf(z[n]);
    ((int*)F)[WS_M + 2 * n + 1] = S[n];
  } else {
    // --- collapsed constants: cl0 (threads 0-127) and cr0 (threads 128-255)
    if (tid < 128) {
      const int c = tid;
      float cl0 = 0.f;
#pragma unroll 8
      for (int i = 0; i < 128; i++)
        cl0 += (bl1[i] + bo1[i]) * Wl2[i * 128 + c];
      F[WS_C + c] = cl0;
      sB[c] = cl0;
    } else {
      const int c = tid - 128;
      float cr0 = 0.f;
#pragma unroll 8
      for (int i = 0; i < 128; i++)
        cr0 += (bl1[i] + bo1[i]) * Wr2[i * 128 + c];
      F[WS_D + c]  = be2[c] + bl2[c] + br2[c] + cr0;
      F[WS_A2 + c] = a2[c];
      sA[c] = bl2[c] + bo2[c];           // O vector (only needed for B0 fold)
    }
    __syncthreads();
    if (tid < 21) {
      float b0 = b_out[tid];
      for (int c = 0; c < 128; c++)
        b0 = fmaf(sA[c], W_out[c * 21 + tid], b0);
      F[WS_B0 + tid] = b0;
    } else if (tid >= 64 && tid < 85) {
      const int u = tid - 64;
      float b1 = 0.f;
      for (int c = 0; c < 128; c++)
        b1 = fmaf(sB[c], W_out[c * 21 + u], b1);
      F[WS_B1 + u] = b1;
    }
  }
}

// ---------------------------------------------------------------------------
// Main (grid 1024 x 256): one wave per node. Round-3 schedule (measured
// best, 159.0) with round-5 correctness:
//  - MFMA A-fragments loaded DIRECTLY from global E (no LDS staging round
//    trip): per (g,q), lane (quad,lid) reads E[n][g*16+lid][q*32+quad*8..+7]
//    as two float4 -> pack to bf16.
//  - Swizzled We2 staged ONCE per block into LDS (32KB), shared by the 4
//    waves: B-fragment reads are conflict-free ds_read_b128.
//  - Edge meta via ONE packed float2 gather per edge from the hot WS_M table.
//  - dvt/a2t computed INSIDE the K-loop (r4/r5 hoist reverted: +16 VGPRs
//    live across peak pressure under the 128-VGPR cap cost ~2.3us measured).
// ---------------------------------------------------------------------------
__global__ __launch_bounds__(256, 4) void pg16_main(
    const float* __restrict__ E, const int* __restrict__ E_idx,
    const float* __restrict__ mask, const void* __restrict__ ws,
    float* __restrict__ out)
{
  __shared__ __align__(16) short ldsW[16384];   // 32 KB: We2 B-fragments

  const short* wsW = (const short*)ws;
  const float* F = (const float*)ws + 8192;
  const int tid  = threadIdx.x;
  const int wave = tid >> 6;
  const int lane = tid & 63;
  const int quad = lane >> 4;
  const int lid  = lane & 15;
  const int n    = blockIdx.x * 4 + wave;
  const float maskn = mask[n];

  // --- edge meta first (heads the longest dependent chain): E_idx -> M[j]
  int jidx = 0;
  if (lane < 32) jidx = E_idx[n * 32 + lane];

  // --- A fragments straight from global E (bulk HBM stream, no LDS)
  const float* rowp = E + (size_t)n * 4096 + (size_t)lid * 128 + quad * 8;
  short8 afr[2][4];
#pragma unroll
  for (int g = 0; g < 2; g++)
#pragma unroll
    for (int q = 0; q < 4; q++) {
      const float* p = rowp + g * 2048 + q * 32;
      const float4 A = *(const float4*)p;
      const float4 B = *(const float4*)(p + 4);
      union { short8 s; unsigned int u[4]; } v;
      v.u[0] = pack2bf(A.x, A.y);
      v.u[1] = pack2bf(A.z, A.w);
      v.u[2] = pack2bf(B.x, B.y);
      v.u[3] = pack2bf(B.z, B.w);
      afr[g][q] = v.s;
    }

  // --- stage swizzled We2 into LDS (linear copy, lane-consecutive 16B)
#pragma unroll
  for (int i = 0; i < 8; i++) {
    const int c = i * 256 + tid;               // short8 chunk id, 2048 total
    *(short8*)(ldsW + c * 8) = *(const short8*)(wsW + c * 8);
  }

  // --- finish meta: one packed float2 gather per edge
  float wkv = 0.f; int rvv = 0;
  const float keyn = F[WS_M + 2 * n];
  if (lane < 32) {
    const float2 mj = *(const float2*)(F + WS_M + 2 * jidx);
    // stable argsort: j ordered before n  <=>  (key[j], j) <lex (key[n], n)
    const int before = (mj.x < keyn) || (mj.x == keyn && jidx < n);
    wkv = before ? maskn : 0.f;
    union { float f; int i; } cv; cv.f = mj.y; rvv = cv.i;
  }
  int rows[2][4]; float wks[2][4];
#pragma unroll
  for (int g = 0; g < 2; g++)
#pragma unroll
    for (int r = 0; r < 4; r++) {
      const int kk = g * 16 + quad * 4 + r;
      rows[g][r] = __shfl(rvv, kk) * 128;
      wks[g][r]  = __shfl(wkv, kk);
    }

  __syncthreads();   // ldsW ready (uniform barrier; afr already in regs)

  // --- K-loop: B tiles from LDS, feed both edge groups
  float part[2][4] = {{0.f, 0.f, 0.f, 0.f}, {0.f, 0.f, 0.f, 0.f}};
#pragma unroll
  for (int t = 0; t < 8; t++) {
    short8 bfr[4];
#pragma unroll
    for (int q = 0; q < 4; q++)
      bfr[q] = *(const short8*)(ldsW + (((q * 8 + t) * 64) + lane) * 8);
    float4v ac0 = {0.f, 0.f, 0.f, 0.f}, ac1 = {0.f, 0.f, 0.f, 0.f};
#pragma unroll
    for (int q = 0; q < 4; q++) {
      ac0 = __builtin_amdgcn_mfma_f32_16x16x32_bf16(afr[0][q], bfr[q], ac0, 0, 0, 0);
      ac1 = __builtin_amdgcn_mfma_f32_16x16x32_bf16(afr[1][q], bfr[q], ac1, 0, 0, 0);
    }
    const int c = t * 16 + lid;
    const float dvt  = F[WS_D + c] + maskn * F[WS_C + c];
    const float a2vt = F[WS_A2 + c];
#pragma unroll
    for (int r = 0; r < 4; r++) {
      float v0 = ac0[r] + dvt + wks[0][r] * F[WS_T + rows[0][r] + c];
      float v1 = ac1[r] + dvt + wks[1][r] * F[WS_T + rows[1][r] + c];
      v0 = fmaxf(v0, 0.f) + 0.2f * fminf(v0, 0.f);   // leaky_relu(0.2)
      v1 = fmaxf(v1, 0.f) + 0.2f * fminf(v1, 0.f);
      part[0][r] = fmaf(v0, a2vt, part[0][r]);
      part[1][r] = fmaf(v1, a2vt, part[1][r]);
    }
  }
  // reduce scores over the 16 c-lanes of each quad
  float sreg[2][4];
#pragma unroll
  for (int g = 0; g < 2; g++)
#pragma unroll
    for (int r = 0; r < 4; r++) {
      float v = part[g][r];
      v += __shfl_xor(v, 1);
      v += __shfl_xor(v, 2);
      v += __shfl_xor(v, 4);
      v += __shfl_xor(v, 8);
      sreg[g][r] = v;   // score for edge kk = g*16 + quad*4 + r (uniform in quad)
    }

  // --- softmax over 32 neighbor scores
  float mx = -1e30f;
#pragma unroll
  for (int g = 0; g < 2; g++)
#pragma unroll
    for (int r = 0; r < 4; r++) mx = fmaxf(mx, sreg[g][r]);
  mx = fmaxf(mx, __shfl_xor(mx, 16));
  mx = fmaxf(mx, __shfl_xor(mx, 32));
  float eg[2][4], esum = 0.f;
#pragma unroll
  for (int g = 0; g < 2; g++)
#pragma unroll
    for (int r = 0; r < 4; r++) {
      eg[g][r] = expf(sreg[g][r] - mx);
      esum += eg[g][r];
    }
  esum += __shfl_xor(esum, 16);
  esum += __shfl_xor(esum, 32);
  const float inv = 1.f / esum;
  float cg[2][4];
#pragma unroll
  for (int g = 0; g < 2; g++)
#pragma unroll
    for (int r = 0; r < 4; r++) cg[g][r] = eg[g][r] * inv * wks[g][r];

  // --- logits via 21x21 table: lg[u] = base0 + maskn*base1 + sum_k cf_k*G[S_k][u]
  float lg = (lane < 21) ? (F[WS_B0 + lane] + maskn * F[WS_B1 + lane]) : -1e30f;
#pragma unroll
  for (int kk = 0; kk < 32; kk++) {
    const int g = kk >> 4, sq = (kk >> 2) & 3, r = kk & 3;
    const float cf = __shfl(cg[g][r], sq * 16);     // broadcast from source quad
    const int row = __shfl(rvv, kk) * 21;           // edge's S from lane kk
    if (lane < 21) lg = fmaf(cf, F[WS_G + row + lane], lg);
  }

  // --- log_softmax over V=21
  float lmx = lg;
  lmx = fmaxf(lmx, __shfl_xor(lmx, 1));
  lmx = fmaxf(lmx, __shfl_xor(lmx, 2));
  lmx = fmaxf(lmx, __shfl_xor(lmx, 4));
  lmx = fmaxf(lmx, __shfl_xor(lmx, 8));
  lmx = fmaxf(lmx, __shfl_xor(lmx, 16));
  float ex = (lane < 21) ? expf(lg - lmx) : 0.f;
  float es = ex;
  es += __shfl_xor(es, 1);
  es += __shfl_xor(es, 2);
  es += __shfl_xor(es, 4);
  es += __shfl_xor(es, 8);
  es += __shfl_xor(es, 16);
  if (lane < 21)
    out[n * 21 + lane] = lg - lmx - logf(es);
}

extern "C" void kernel_launch(void* const* d_in, const int* in_sizes, int n_in,
                              void* d_out, int out_size, void* d_ws, size_t ws_size,
                              hipStream_t stream)
{
  const float* E       = (const float*)d_in[0];
  const int*   E_idx   = (const int*)d_in[1];
  const int*   S       = (const int*)d_in[2];
  const float* mask    = (const float*)d_in[3];
  const float* chain_M = (const float*)d_in[4];
  const float* z       = (const float*)d_in[5];
  const float* bl1     = (const float*)d_in[7];
  const float* bo1     = (const float*)d_in[13];
  const float* Wl2     = (const float*)d_in[14];
  const float* bl2     = (const float*)d_in[15];
  const float* Wr2     = (const float*)d_in[16];
  const float* br2     = (const float*)d_in[17];
  const float* We2     = (const float*)d_in[18];
  const float* be2     = (const float*)d_in[19];
  const float* a2      = (const float*)d_in[20];
  const float* bo2     = (const float*)d_in[21];
  const float* W_s     = (const float*)d_in[22];
  const float* W_out   = (const float*)d_in[23];
  const float* b_out   = (const float*)d_in[24];

  pg16_pre<<<102, 256, 0, stream>>>(Wl2, Wr2, We2, bl1, bl2, br2, be2, a2,
                                    bo1, bo2, W_s, mask, chain_M, z, S,
                                    W_out, b_out, d_ws);
  pg16_main<<<1024, 256, 0, stream>>>(E, E_idx, mask, d_ws, (float*)d_out);
}